// Round 7
// baseline (334.407 us; speedup 1.0000x reference)
//
#include <hip/hip_runtime.h>

// Problem constants (fixed by reference)
#define B_    2
#define NH_   4
#define T_    8
#define H_    14
#define W_    14
#define HW_   196             // H*W
#define HD_   96
#define DIM_  384
#define N_    1568            // T*H*W
#define BH_   (B_*NH_)        // 8
#define BN_   (B_*N_)         // 3136
#define BHN_  (BH_*N_)        // 12544
#define CAUG_ 160             // 96 + 36 one-hot/bias + 28 pad

typedef unsigned short bf_t;
typedef unsigned int   u32;
typedef __attribute__((ext_vector_type(8))) short bf16x8;
typedef __attribute__((ext_vector_type(4))) float f32x4;

#define LOG2E 1.4426950408889634f
#define QSCALE_LOG2E 0.14724445f   /* 96^-0.5 * log2(e) */

static __device__ __forceinline__ float lo16(u32 v){ union{u32 i; float f;}x; x.i = v<<16;           return x.f; }
static __device__ __forceinline__ float hi16(u32 v){ union{u32 i; float f;}x; x.i = v & 0xffff0000u; return x.f; }
static __device__ __forceinline__ float b2f(bf_t v){ union{u32 i; float f;}x; x.i = ((u32)v)<<16;    return x.f; }
static __device__ __forceinline__ bf_t  f2b(float f){
  union{float f; u32 i;} x; x.f = f;
  return (bf_t)((x.i + 0x7fffu + ((x.i>>16)&1u)) >> 16);   // RNE
}
static __device__ __forceinline__ u32 pack2(float a, float b){
  return (u32)f2b(a) | ((u32)f2b(b) << 16);
}

// ---------------------------------------------------------------------------
// K0: cast x / qkv_w / proj_w fp32 -> bf16 (region-concatenated flat loop).
// ---------------------------------------------------------------------------
#define NA_ (BN_*DIM_)        // 1,204,224
#define NB_ (3*DIM_*DIM_)     //   442,368
#define NC_ (DIM_*DIM_)       //   147,456
#define CAST_BLOCKS ((NA_+NB_+NC_)/4/256)   // 1752 exactly

__global__ __launch_bounds__(256) void k_cast(
    const float* __restrict__ a, bf_t* __restrict__ ad,
    const float* __restrict__ b, bf_t* __restrict__ bd,
    const float* __restrict__ c, bf_t* __restrict__ cd){
  const int i = blockIdx.x*256 + threadIdx.x;     // float4 index
  const int i4 = i*4;
  const float4* src; bf_t* dst; int off;
  if (i4 < NA_)           { src = (const float4*)a; dst = ad; off = i; }
  else if (i4 < NA_+NB_)  { src = (const float4*)b; dst = bd; off = i - NA_/4; }
  else                    { src = (const float4*)c; dst = cd; off = i - (NA_+NB_)/4; }
  const float4 v = src[off];
  ushort4 o; o.x = f2b(v.x); o.y = f2b(v.y); o.z = f2b(v.z); o.w = f2b(v.w);
  ((ushort4*)dst)[off] = o;
}

// ---------------------------------------------------------------------------
// K1: QKV GEMM via MFMA. C[3136,1152] = Xb[3136,384] . Wb[1152,384]^T (bf16).
// ---------------------------------------------------------------------------
__global__ __launch_bounds__(256) void k_qkv(const bf_t* __restrict__ Xb,
    const bf_t* __restrict__ Wb,
    bf_t* __restrict__ q, bf_t* __restrict__ k, bf_t* __restrict__ v){
  const int wid = threadIdx.x >> 6, lane = threadIdx.x & 63;
  const int wr = wid & 1, wc = wid >> 1;
  const int nl = lane & 15, quad = lane >> 4;
  const int r0 = blockIdx.x*64 + wr*32;
  const int c0 = blockIdx.y*128 + wc*64;
  f32x4 acc[2][4];
  #pragma unroll
  for (int i = 0; i < 2; ++i)
    #pragma unroll
    for (int j = 0; j < 4; ++j) acc[i][j] = (f32x4){0.f,0.f,0.f,0.f};
  const bf_t* A0 = Xb + (size_t)(r0 + nl)*DIM_ + quad*8;
  const bf_t* B0 = Wb + (size_t)(c0 + nl)*DIM_ + quad*8;
  #pragma unroll 2
  for (int k0 = 0; k0 < 12; ++k0){
    const bf16x8 a0 = *(const bf16x8*)(A0 + k0*32);
    const bf16x8 a1 = *(const bf16x8*)(A0 + 16*DIM_ + k0*32);
    bf16x8 bf[4];
    #pragma unroll
    for (int j = 0; j < 4; ++j) bf[j] = *(const bf16x8*)(B0 + (size_t)j*16*DIM_ + k0*32);
    #pragma unroll
    for (int j = 0; j < 4; ++j){
      acc[0][j] = __builtin_amdgcn_mfma_f32_16x16x32_bf16(a0, bf[j], acc[0][j], 0, 0, 0);
      acc[1][j] = __builtin_amdgcn_mfma_f32_16x16x32_bf16(a1, bf[j], acc[1][j], 0, 0, 0);
    }
  }
  #pragma unroll
  for (int i = 0; i < 2; ++i){
    #pragma unroll
    for (int r = 0; r < 4; ++r){
      const int m  = r0 + i*16 + quad*4 + r;
      const int bb = m / N_, nn = m % N_;
      #pragma unroll
      for (int j = 0; j < 4; ++j){
        const int col = c0 + j*16 + nl;
        const int s = col / DIM_, rem = col - s*DIM_;
        const int head = rem / HD_, hc = rem % HD_;
        bf_t* dst = (s==0) ? q : (s==1) ? k : v;
        dst[((size_t)(bb*NH_ + head)*N_ + nn)*HD_ + hc] = f2b(acc[i][j][r]);
      }
    }
  }
}

// ---------------------------------------------------------------------------
// Conv3d + LayerNorm core: lane < 48 owns channel pair (2l, 2l+1) of token n
// of tensor `base` ([N,96] bf16). Wave-butterfly LN, no LDS.
// Returns packed result via (y0, y1).
// ---------------------------------------------------------------------------
static __device__ __forceinline__ void conv_ln(
    const bf_t* __restrict__ base, const float* __restrict__ wc,
    const float* __restrict__ g, const float* __restrict__ be,
    int n, int lane, float& y0, float& y1){
  const int tt = n / HW_; const int rm = n % HW_;
  const int hh = rm / W_, ww = rm % W_;
  float v0 = 0.f, v1 = 0.f;
  if (lane < 48){
    const int c0 = 2*lane;
    #pragma unroll
    for (int dt=-1; dt<=1; ++dt){ const int t2=tt+dt; if((unsigned)t2 >= (unsigned)T_) continue;
      #pragma unroll
      for (int dh=-1; dh<=1; ++dh){ const int h2=hh+dh; if((unsigned)h2 >= (unsigned)H_) continue;
        #pragma unroll
        for (int dw=-1; dw<=1; ++dw){ const int w2=ww+dw; if((unsigned)w2 >= (unsigned)W_) continue;
          const int j = (dt+1)*9 + (dh+1)*3 + (dw+1);
          const u32 u = *(const u32*)(base + (size_t)(t2*HW_ + h2*W_ + w2)*HD_ + c0);
          v0 = fmaf(wc[c0*27 + j],       lo16(u), v0);
          v1 = fmaf(wc[(c0+1)*27 + j],   hi16(u), v1);
        }}}
  }
  float s  = v0 + v1;
  float s2 = v0*v0 + v1*v1;
  #pragma unroll
  for (int off = 32; off > 0; off >>= 1){
    s  += __shfl_xor(s,  off);
    s2 += __shfl_xor(s2, off);
  }
  const float mean = s * (1.f/HD_);
  const float var  = fmaxf(s2*(1.f/HD_) - mean*mean, 0.f);
  const float rstd = rsqrtf(var + 1e-6f);
  if (lane < 48){
    const int c0 = 2*lane;
    y0 = (v0 - mean)*rstd*g[c0]   + be[c0];
    y1 = (v1 - mean)*rstd*g[c0+1] + be[c0+1];
  }
}

// ---------------------------------------------------------------------------
// K2a: pool for q and k. One wave per token; grid (BHN/4, 2), block 256.
// y=0: qp + Qaug[0..95] (scaled); y=1: Kaug[0..95] + one-hot ch 96..159.
// ---------------------------------------------------------------------------
__global__ __launch_bounds__(256) void k_pool_qk(
    const bf_t* __restrict__ qr_, const bf_t* __restrict__ kr_,
    const float* __restrict__ wq, const float* __restrict__ wk,
    const float* __restrict__ gq, const float* __restrict__ bq,
    const float* __restrict__ gk, const float* __restrict__ bk,
    bf_t* __restrict__ qp, bf_t* __restrict__ Qaug, bf_t* __restrict__ Kaug){
  const int wid = threadIdx.x >> 6, lane = threadIdx.x & 63;
  const int token = blockIdx.x*4 + wid;
  const int which = blockIdx.y;
  const int bh = token / N_, n = token % N_;
  const bf_t*  in = (which==0)? qr_ : kr_;
  const float* wc = (which==0)? wq  : wk;
  const float* g  = (which==0)? gq  : gk;
  const float* be = (which==0)? bq  : bk;
  float y0 = 0.f, y1 = 0.f;
  conv_ln(in + (size_t)bh*N_*HD_, wc, g, be, n, lane, y0, y1);
  if (which==0){
    if (lane < 48){
      ((u32*)qp)  [(size_t)token*48 + lane] = pack2(y0, y1);
      ((u32*)Qaug)[(size_t)token*80 + lane] = pack2(y0*QSCALE_LOG2E, y1*QSCALE_LOG2E);
    }
  } else {
    if (lane < 48){
      ((u32*)Kaug)[(size_t)token*80 + lane] = pack2(y0, y1);
    } else {
      // one-hot channels 96..159, 4 per lane
      const int tt = n / HW_; const int rm = n % HW_;
      const int hh = rm / W_, ww = rm % W_;
      const int j0 = 4*(lane - 48);
      u32 p[2];
      #pragma unroll
      for (int h2 = 0; h2 < 2; ++h2){
        u32 w_ = 0;
        #pragma unroll
        for (int e = 0; e < 2; ++e){
          const int jj = j0 + 2*h2 + e;
          bool on = (jj < 14) ? (jj == hh) : (jj < 28) ? (jj-14 == ww)
                   : (jj < 36) ? (jj-28 == tt) : false;
          if (on) w_ |= (0x3F80u << (16*e));
        }
        p[h2] = w_;
      }
      *(uint2*)(Kaug + (size_t)token*CAUG_ + HD_ + j0) = make_uint2(p[0], p[1]);
    }
  }
}

// ---------------------------------------------------------------------------
// K2b: pool for v, writing transposed Vt [BH][96][N]. One wave per 8
// consecutive tokens; lane keeps 8 packed results in regs, then writes its
// two channel rows as one uint4 (16B, 8 tokens) each. Grid BHN/32, block 256.
// ---------------------------------------------------------------------------
__global__ __launch_bounds__(256) void k_pool_v(
    const bf_t* __restrict__ vr_, const float* __restrict__ wv,
    const float* __restrict__ gv, const float* __restrict__ bv,
    bf_t* __restrict__ Vt){
  const int wid = threadIdx.x >> 6, lane = threadIdx.x & 63;
  const int tok0 = (blockIdx.x*4 + wid)*8;
  const int bh = tok0 / N_, n0 = tok0 % N_;
  const bf_t* base = vr_ + (size_t)bh*N_*HD_;
  u32 acc[8];
  #pragma unroll 1
  for (int t8 = 0; t8 < 8; ++t8){
    float y0 = 0.f, y1 = 0.f;
    conv_ln(base, wv, gv, bv, n0 + t8, lane, y0, y1);
    acc[t8] = pack2(y0, y1);
  }
  if (lane < 48){
    u32 lo[4], hi[4];
    #pragma unroll
    for (int i = 0; i < 4; ++i){
      lo[i] = (acc[2*i] & 0xffffu)  | (acc[2*i+1] << 16);
      hi[i] = (acc[2*i] >> 16)      | (acc[2*i+1] & 0xffff0000u);
    }
    bf_t* r0 = Vt + ((size_t)bh*HD_ + 2*lane)*N_ + n0;
    *(uint4*)r0        = make_uint4(lo[0], lo[1], lo[2], lo[3]);
    *(uint4*)(r0 + N_) = make_uint4(hi[0], hi[1], hi[2], hi[3]);
  }
}

// ---------------------------------------------------------------------------
// K3: rel-pos bias dots -> Qaug channels 96..131 (x log2e); 132..159 zeroed.
// ---------------------------------------------------------------------------
__global__ __launch_bounds__(64) void k_rel(const bf_t* __restrict__ qp,
    const float* __restrict__ rph, const float* __restrict__ rpw,
    const float* __restrict__ rpt, bf_t* __restrict__ Qaug){
  const int token = blockIdx.x;
  const int n = token % N_;
  const int tt = n / HW_; const int rm = n % HW_;
  const int hh = rm / W_, ww = rm % W_;
  __shared__ float qs[HD_];
  const int lane = threadIdx.x;
  if (lane < 48){
    const u32 u = ((const u32*)qp)[(size_t)token*48 + lane];
    qs[2*lane] = lo16(u); qs[2*lane+1] = hi16(u);
  }
  __syncthreads();
  if (lane < 36){
    const float* tb; int idx;
    if (lane < 14)      { tb = rph; idx = hh - lane      + 13; }
    else if (lane < 28) { tb = rpw; idx = ww - (lane-14) + 13; }
    else                { tb = rpt; idx = tt - (lane-28) +  7; }
    const float4* t4 = (const float4*)(tb + (size_t)idx*HD_);
    float acc = 0.f;
    #pragma unroll
    for (int i = 0; i < 24; ++i){
      const float4 rv = t4[i];
      acc += qs[4*i]*rv.x + qs[4*i+1]*rv.y + qs[4*i+2]*rv.z + qs[4*i+3]*rv.w;
    }
    Qaug[(size_t)token*CAUG_ + HD_ + lane] = f2b(acc * LOG2E);
  } else {
    Qaug[(size_t)token*CAUG_ + HD_ + lane] = 0;
  }
}

// ---------------------------------------------------------------------------
// K4: MFMA flash attention, in-block split-K (4 waves share a 16-row q-tile).
// ---------------------------------------------------------------------------
__global__ __launch_bounds__(256) void k_attn(
    const bf_t* __restrict__ Qaug, const bf_t* __restrict__ Kaug,
    const bf_t* __restrict__ Vt, const bf_t* __restrict__ qp,
    bf_t* __restrict__ attb){
  __shared__ __align__(16) short Pb[4][16][40];   // per-wave P tile (+8 pad)
  __shared__ float Os[4][16][96];                 // per-wave partial O
  __shared__ float ms[4][16], ls[4][16];          // per-wave partial m, l
  const int wid = threadIdx.x >> 6, lane = threadIdx.x & 63;
  const int bh = blockIdx.x / 98, qt = blockIdx.x % 98;
  const int q0 = qt*16;
  const int nl = lane & 15, quad = lane >> 4;

  bf16x8 qa[5];
  {
    const bf_t* Qrow = Qaug + ((size_t)bh*N_ + q0 + nl)*CAUG_ + quad*8;
    #pragma unroll
    for (int i = 0; i < 5; ++i) qa[i] = *(const bf16x8*)(Qrow + i*32);
  }
  const bf_t* Kb = Kaug + (size_t)bh*N_*CAUG_;
  const bf_t* Vb = Vt   + (size_t)bh*HD_*N_;
  short* Pw = &Pb[wid][0][0];

  f32x4 O[6];
  #pragma unroll
  for (int i = 0; i < 6; ++i) O[i] = (f32x4){0.f,0.f,0.f,0.f};
  float mc[4]   = {0.f,0.f,0.f,0.f};
  float rmax[4] = {-3e38f,-3e38f,-3e38f,-3e38f};
  float l[4]    = {0.f,0.f,0.f,0.f};

  auto s_tile = [&](int k0, int half){
    const bf_t* Krow = Kb + (size_t)(k0 + nl)*CAUG_ + quad*8;
    f32x4 s = (f32x4){0.f,0.f,0.f,0.f};
    #pragma unroll
    for (int i = 0; i < 5; ++i)
      s = __builtin_amdgcn_mfma_f32_16x16x32_bf16(qa[i], *(const bf16x8*)(Krow + i*32), s, 0, 0, 0);
    #pragma unroll
    for (int r = 0; r < 4; ++r){
      rmax[r] = fmaxf(rmax[r], s[r]);
      const float p = exp2f(s[r] - mc[r]);
      l[r] += p;
      Pw[(quad*4 + r)*40 + half*16 + nl] = (short)f2b(p);
    }
  };
  auto rescale = [&](){
    #pragma unroll
    for (int r = 0; r < 4; ++r){
      float tm = rmax[r];
      tm = fmaxf(tm, __shfl_xor(tm, 1));
      tm = fmaxf(tm, __shfl_xor(tm, 2));
      tm = fmaxf(tm, __shfl_xor(tm, 4));
      tm = fmaxf(tm, __shfl_xor(tm, 8));
      const float mn = fmaxf(mc[r], tm);
      const float al = exp2f(mc[r] - mn);
      mc[r] = mn; l[r] *= al;
      #pragma unroll
      for (int ct = 0; ct < 6; ++ct) O[ct][r] *= al;
    }
  };

  const int starts[5] = {0, 26, 52, 76, 98};
  const int t0 = starts[wid], npairs = (starts[wid+1] - t0) >> 1;
  #pragma unroll 1
  for (int pi = 0; pi < npairs; ++pi){
    const int k0 = (t0 + 2*pi)*16;
    s_tile(k0,      0);
    s_tile(k0 + 16, 1);
    const bf16x8 pa = *(const bf16x8*)(Pw + nl*40 + quad*8);
    const bf_t* Vrow = Vb + (size_t)nl*N_ + k0 + quad*8;
    #pragma unroll
    for (int ct = 0; ct < 6; ++ct)
      O[ct] = __builtin_amdgcn_mfma_f32_16x16x32_bf16(pa, *(const bf16x8*)(Vrow + (size_t)ct*16*N_), O[ct], 0, 0, 0);
    if ((pi % 7) == 6 || pi == npairs-1) rescale();
  }

  #pragma unroll
  for (int r = 0; r < 4; ++r){
    float ls_ = l[r];
    ls_ += __shfl_xor(ls_, 1); ls_ += __shfl_xor(ls_, 2);
    ls_ += __shfl_xor(ls_, 4); ls_ += __shfl_xor(ls_, 8);
    if (nl == 0){ ms[wid][quad*4 + r] = mc[r]; ls[wid][quad*4 + r] = ls_; }
    #pragma unroll
    for (int ct = 0; ct < 6; ++ct) Os[wid][quad*4 + r][ct*16 + nl] = O[ct][r];
  }
  __syncthreads();

  const int bb = bh >> 2, head = bh & 3;
  for (int e = threadIdx.x; e < 16*96; e += 256){
    const int row = e / 96, col = e % 96;
    const float m0 = ms[0][row], m1 = ms[1][row], m2 = ms[2][row], m3 = ms[3][row];
    const float mx = fmaxf(fmaxf(m0, m1), fmaxf(m2, m3));
    const float w0 = exp2f(m0 - mx), w1 = exp2f(m1 - mx),
                w2 = exp2f(m2 - mx), w3 = exp2f(m3 - mx);
    const float L = w0*ls[0][row] + w1*ls[1][row] + w2*ls[2][row] + w3*ls[3][row];
    const float A = w0*Os[0][row][col] + w1*Os[1][row][col]
                  + w2*Os[2][row][col] + w3*Os[3][row][col];
    const int qg = q0 + row;
    const float val = A/L + b2f(qp[((size_t)bh*N_ + qg)*HD_ + col]);
    attb[((size_t)(bb*N_ + qg))*DIM_ + head*HD_ + col] = f2b(val);
  }
}

// ---------------------------------------------------------------------------
// K5: output projection via MFMA: d_out[3136,384] = attb . Wpb^T + pb (fp32).
// ---------------------------------------------------------------------------
__global__ __launch_bounds__(256) void k_proj(const bf_t* __restrict__ Ab,
    const bf_t* __restrict__ Wpb, const float* __restrict__ pb,
    float* __restrict__ out){
  const int wid = threadIdx.x >> 6, lane = threadIdx.x & 63;
  const int wr = wid & 1, wc = wid >> 1;
  const int nl = lane & 15, quad = lane >> 4;
  const int r0 = blockIdx.x*64 + wr*32;
  const int c0 = blockIdx.y*128 + wc*64;
  f32x4 acc[2][4];
  #pragma unroll
  for (int i = 0; i < 2; ++i)
    #pragma unroll
    for (int j = 0; j < 4; ++j) acc[i][j] = (f32x4){0.f,0.f,0.f,0.f};
  const bf_t* A0 = Ab  + (size_t)(r0 + nl)*DIM_ + quad*8;
  const bf_t* B0 = Wpb + (size_t)(c0 + nl)*DIM_ + quad*8;
  #pragma unroll 2
  for (int k0 = 0; k0 < 12; ++k0){
    const bf16x8 a0 = *(const bf16x8*)(A0 + k0*32);
    const bf16x8 a1 = *(const bf16x8*)(A0 + 16*DIM_ + k0*32);
    bf16x8 bf[4];
    #pragma unroll
    for (int j = 0; j < 4; ++j) bf[j] = *(const bf16x8*)(B0 + (size_t)j*16*DIM_ + k0*32);
    #pragma unroll
    for (int j = 0; j < 4; ++j){
      acc[0][j] = __builtin_amdgcn_mfma_f32_16x16x32_bf16(a0, bf[j], acc[0][j], 0, 0, 0);
      acc[1][j] = __builtin_amdgcn_mfma_f32_16x16x32_bf16(a1, bf[j], acc[1][j], 0, 0, 0);
    }
  }
  #pragma unroll
  for (int i = 0; i < 2; ++i){
    #pragma unroll
    for (int r = 0; r < 4; ++r){
      const int m = r0 + i*16 + quad*4 + r;
      #pragma unroll
      for (int j = 0; j < 4; ++j){
        const int col = c0 + j*16 + nl;
        out[(size_t)m*DIM_ + col] = acc[i][j][r] + pb[col];
      }
    }
  }
}

// ---------------------------------------------------------------------------
extern "C" void kernel_launch(void* const* d_in, const int* in_sizes, int n_in,
                              void* d_out, int out_size, void* d_ws, size_t ws_size,
                              hipStream_t stream){
  const float* x      = (const float*)d_in[0];
  const float* qkv_w  = (const float*)d_in[1];
  const float* proj_w = (const float*)d_in[2];
  const float* proj_b = (const float*)d_in[3];
  const float* pqw    = (const float*)d_in[4];
  const float* pkw    = (const float*)d_in[5];
  const float* pvw    = (const float*)d_in[6];
  const float* nqw    = (const float*)d_in[7];
  const float* nqb    = (const float*)d_in[8];
  const float* nkw    = (const float*)d_in[9];
  const float* nkb    = (const float*)d_in[10];
  const float* nvw    = (const float*)d_in[11];
  const float* nvb    = (const float*)d_in[12];
  const float* rph    = (const float*)d_in[13];
  const float* rpw    = (const float*)d_in[14];
  const float* rpt    = (const float*)d_in[15];

  // Workspace (bytes), ~23.7 MB total. attb overlays raw_q after pooling.
  char* p = (char*)d_ws;
  const size_t RAW = (size_t)BH_*N_*HD_*2;       // 2,408,448 B
  const size_t AUG = (size_t)BH_*N_*CAUG_*2;     // 4,014,080 B
  bf_t* xb     = (bf_t*)(p);                     // 2,408,448 B
  bf_t* wqkvb  = (bf_t*)(p + RAW);               //   884,736 B
  bf_t* wprojb = (bf_t*)(p + RAW + 884736);      //   294,912 B
  char* p2 = p + RAW + 884736 + 294912;
  bf_t* raw_q  = (bf_t*)(p2);
  bf_t* raw_k  = (bf_t*)(p2 + RAW);
  bf_t* raw_v  = (bf_t*)(p2 + 2*RAW);
  bf_t* attb   = raw_q;                          // overlays raw_q after pooling
  bf_t* qp     = (bf_t*)(p2 + 3*RAW);
  bf_t* Qaug   = (bf_t*)(p2 + 4*RAW);
  bf_t* Kaug   = (bf_t*)(p2 + 4*RAW + AUG);
  bf_t* Vt     = (bf_t*)(p2 + 4*RAW + 2*AUG);

  k_cast   <<<CAST_BLOCKS,        256, 0, stream>>>(x, xb, qkv_w, wqkvb, proj_w, wprojb);
  k_qkv    <<<dim3(BN_/64, 9),    256, 0, stream>>>(xb, wqkvb, raw_q, raw_k, raw_v);
  k_pool_qk<<<dim3(BHN_/4, 2),    256, 0, stream>>>(raw_q, raw_k, pqw, pkw,
                                                    nqw, nqb, nkw, nkb,
                                                    qp, Qaug, Kaug);
  k_pool_v <<<BHN_/32,            256, 0, stream>>>(raw_v, pvw, nvw, nvb, Vt);
  k_rel    <<<BHN_,                64, 0, stream>>>(qp, rph, rpw, rpt, Qaug);
  k_attn   <<<BH_*98,             256, 0, stream>>>(Qaug, Kaug, Vt, qp, attb);
  k_proj   <<<dim3(BN_/64, 3),    256, 0, stream>>>(attb, wprojb, proj_b, (float*)d_out);
}

// Round 8
// 257.976 us; speedup vs baseline: 1.2963x; 1.2963x over previous
//
#include <hip/hip_runtime.h>

// Problem constants (fixed by reference)
#define B_    2
#define NH_   4
#define T_    8
#define H_    14
#define W_    14
#define HW_   196             // H*W
#define HD_   96
#define DIM_  384
#define N_    1568            // T*H*W
#define BH_   (B_*NH_)        // 8
#define BN_   (B_*N_)         // 3136
#define BHN_  (BH_*N_)        // 12544
#define CAUG_ 160             // 96 + 36 one-hot/bias + 28 pad

typedef unsigned short bf_t;
typedef unsigned int   u32;
typedef __attribute__((ext_vector_type(8))) short bf16x8;
typedef __attribute__((ext_vector_type(4))) float f32x4;

#define LOG2E 1.4426950408889634f
#define QSCALE_LOG2E 0.14724445f   /* 96^-0.5 * log2(e) */

static __device__ __forceinline__ float lo16(u32 v){ union{u32 i; float f;}x; x.i = v<<16;           return x.f; }
static __device__ __forceinline__ float hi16(u32 v){ union{u32 i; float f;}x; x.i = v & 0xffff0000u; return x.f; }
static __device__ __forceinline__ float b2f(bf_t v){ union{u32 i; float f;}x; x.i = ((u32)v)<<16;    return x.f; }
static __device__ __forceinline__ bf_t  f2b(float f){
  union{float f; u32 i;} x; x.f = f;
  return (bf_t)((x.i + 0x7fffu + ((x.i>>16)&1u)) >> 16);   // RNE
}
static __device__ __forceinline__ u32 pack2(float a, float b){
  return (u32)f2b(a) | ((u32)f2b(b) << 16);
}

// ---------------------------------------------------------------------------
// K0: cast x / qkv_w / proj_w fp32 -> bf16 (region-concatenated flat loop).
// ---------------------------------------------------------------------------
#define NA_ (BN_*DIM_)        // 1,204,224
#define NB_ (3*DIM_*DIM_)     //   442,368
#define NC_ (DIM_*DIM_)       //   147,456
#define CAST_BLOCKS ((NA_+NB_+NC_)/4/256)   // 1752 exactly

__global__ __launch_bounds__(256) void k_cast(
    const float* __restrict__ a, bf_t* __restrict__ ad,
    const float* __restrict__ b, bf_t* __restrict__ bd,
    const float* __restrict__ c, bf_t* __restrict__ cd){
  const int i = blockIdx.x*256 + threadIdx.x;     // float4 index
  const int i4 = i*4;
  const float4* src; bf_t* dst; int off;
  if (i4 < NA_)           { src = (const float4*)a; dst = ad; off = i; }
  else if (i4 < NA_+NB_)  { src = (const float4*)b; dst = bd; off = i - NA_/4; }
  else                    { src = (const float4*)c; dst = cd; off = i - (NA_+NB_)/4; }
  const float4 v = src[off];
  ushort4 o; o.x = f2b(v.x); o.y = f2b(v.y); o.z = f2b(v.z); o.w = f2b(v.w);
  ((ushort4*)dst)[off] = o;
}

// ---------------------------------------------------------------------------
// K0b: transpose conv weights [96][27] -> [27][96] fp32 (3 tensors).
// ---------------------------------------------------------------------------
__global__ __launch_bounds__(256) void k_prep(
    const float* __restrict__ wq, const float* __restrict__ wk,
    const float* __restrict__ wv, float* __restrict__ tq,
    float* __restrict__ tk, float* __restrict__ tv){
  const int idx = blockIdx.x*256 + threadIdx.x;
  if (idx >= 3*HD_*27) return;
  const int t = idx / (HD_*27), rem = idx % (HD_*27);
  const int c = rem / 27, j = rem % 27;
  const float* s = (t==0)? wq : (t==1)? wk : wv;
  float* d       = (t==0)? tq : (t==1)? tk : tv;
  d[j*HD_ + c] = s[c*27 + j];
}

// ---------------------------------------------------------------------------
// K1: QKV GEMM via MFMA. C[3136,1152] = Xb[3136,384] . Wb[1152,384]^T (bf16).
// ---------------------------------------------------------------------------
__global__ __launch_bounds__(256) void k_qkv(const bf_t* __restrict__ Xb,
    const bf_t* __restrict__ Wb,
    bf_t* __restrict__ q, bf_t* __restrict__ k, bf_t* __restrict__ v){
  const int wid = threadIdx.x >> 6, lane = threadIdx.x & 63;
  const int wr = wid & 1, wc = wid >> 1;
  const int nl = lane & 15, quad = lane >> 4;
  const int r0 = blockIdx.x*64 + wr*32;
  const int c0 = blockIdx.y*128 + wc*64;
  f32x4 acc[2][4];
  #pragma unroll
  for (int i = 0; i < 2; ++i)
    #pragma unroll
    for (int j = 0; j < 4; ++j) acc[i][j] = (f32x4){0.f,0.f,0.f,0.f};
  const bf_t* A0 = Xb + (size_t)(r0 + nl)*DIM_ + quad*8;
  const bf_t* B0 = Wb + (size_t)(c0 + nl)*DIM_ + quad*8;
  #pragma unroll 2
  for (int k0 = 0; k0 < 12; ++k0){
    const bf16x8 a0 = *(const bf16x8*)(A0 + k0*32);
    const bf16x8 a1 = *(const bf16x8*)(A0 + 16*DIM_ + k0*32);
    bf16x8 bf[4];
    #pragma unroll
    for (int j = 0; j < 4; ++j) bf[j] = *(const bf16x8*)(B0 + (size_t)j*16*DIM_ + k0*32);
    #pragma unroll
    for (int j = 0; j < 4; ++j){
      acc[0][j] = __builtin_amdgcn_mfma_f32_16x16x32_bf16(a0, bf[j], acc[0][j], 0, 0, 0);
      acc[1][j] = __builtin_amdgcn_mfma_f32_16x16x32_bf16(a1, bf[j], acc[1][j], 0, 0, 0);
    }
  }
  #pragma unroll
  for (int i = 0; i < 2; ++i){
    #pragma unroll
    for (int r = 0; r < 4; ++r){
      const int m  = r0 + i*16 + quad*4 + r;
      const int bb = m / N_, nn = m % N_;
      #pragma unroll
      for (int j = 0; j < 4; ++j){
        const int col = c0 + j*16 + nl;
        const int s = col / DIM_, rem = col - s*DIM_;
        const int head = rem / HD_, hc = rem % HD_;
        bf_t* dst = (s==0) ? q : (s==1) ? k : v;
        dst[((size_t)(bb*NH_ + head)*N_ + nn)*HD_ + hc] = f2b(acc[i][j][r]);
      }
    }
  }
}

// ---------------------------------------------------------------------------
// Conv core, ILP-pipelined: all 27 neighbor u32 loads issued before any use.
// wgt = per-lane 27 float2 taps (hoisted by caller). Lane owns channel pair
// c0 = 2*lane (lane<48); lanes 48..63 produce garbage the caller must mask.
// ---------------------------------------------------------------------------
static __device__ __forceinline__ void conv_core(
    const bf_t* __restrict__ base, const float2* __restrict__ wgt,
    int n, int c0, float& v0, float& v1){
  const int tt = n / HW_; const int rm = n % HW_;
  const int hh = rm / W_, ww = rm % W_;
  u32 data[27];
  #pragma unroll
  for (int j = 0; j < 27; ++j){
    const int dt = j/9 - 1, dh = (j%9)/3 - 1, dw = j%3 - 1;
    const int t2 = tt+dt, h2 = hh+dh, w2 = ww+dw;
    const bool ok = ((unsigned)t2 < (unsigned)T_) && ((unsigned)h2 < (unsigned)H_)
                 && ((unsigned)w2 < (unsigned)W_);
    const int nn = ok ? (t2*HW_ + h2*W_ + w2) : n;     // clamped, always valid
    const u32 d = *(const u32*)(base + (size_t)nn*HD_ + c0);
    data[j] = ok ? d : 0u;
  }
  v0 = 0.f; v1 = 0.f;
  #pragma unroll
  for (int j = 0; j < 27; ++j){
    v0 = fmaf(wgt[j].x, lo16(data[j]), v0);
    v1 = fmaf(wgt[j].y, hi16(data[j]), v1);
  }
}

// Wave-butterfly LayerNorm from per-lane pair sums (lanes>=48 must pass 0).
static __device__ __forceinline__ void ln_butterfly(
    float v0, float v1, float& mean, float& rstd){
  float s  = v0 + v1;
  float s2 = v0*v0 + v1*v1;
  #pragma unroll
  for (int off = 32; off > 0; off >>= 1){
    s  += __shfl_xor(s,  off);
    s2 += __shfl_xor(s2, off);
  }
  mean = s * (1.f/HD_);
  const float var = fmaxf(s2*(1.f/HD_) - mean*mean, 0.f);
  rstd = rsqrtf(var + 1e-6f);
}

// ---------------------------------------------------------------------------
// K2a: pool for q and k. One wave per token; grid (BHN/4, 2), block 256.
// y=0: qp + Qaug[0..95] (scaled); y=1: Kaug[0..95] + one-hot ch 96..159.
// ---------------------------------------------------------------------------
__global__ __launch_bounds__(256) void k_pool_qk(
    const bf_t* __restrict__ qr_, const bf_t* __restrict__ kr_,
    const float* __restrict__ wtq, const float* __restrict__ wtk,
    const float* __restrict__ gq, const float* __restrict__ bq,
    const float* __restrict__ gk, const float* __restrict__ bk,
    bf_t* __restrict__ qp, bf_t* __restrict__ Qaug, bf_t* __restrict__ Kaug){
  const int wid = threadIdx.x >> 6, lane = threadIdx.x & 63;
  const int token = blockIdx.x*4 + wid;
  const int which = blockIdx.y;
  const int bh = token / N_, n = token % N_;
  const bf_t*  in = (which==0)? qr_ : kr_;
  const float* wt = (which==0)? wtq : wtk;
  const float* g  = (which==0)? gq  : gk;
  const float* be = (which==0)? bq  : bk;
  const int c0 = (lane < 48) ? 2*lane : 0;
  float2 wgt[27];
  #pragma unroll
  for (int j = 0; j < 27; ++j) wgt[j] = *(const float2*)(wt + j*HD_ + c0);
  float v0, v1;
  conv_core(in + (size_t)bh*N_*HD_, wgt, n, c0, v0, v1);
  if (lane >= 48){ v0 = 0.f; v1 = 0.f; }
  float mean, rstd;
  ln_butterfly(v0, v1, mean, rstd);
  if (which==0){
    if (lane < 48){
      const float y0 = (v0 - mean)*rstd*g[c0]   + be[c0];
      const float y1 = (v1 - mean)*rstd*g[c0+1] + be[c0+1];
      ((u32*)qp)  [(size_t)token*48 + lane] = pack2(y0, y1);
      ((u32*)Qaug)[(size_t)token*80 + lane] = pack2(y0*QSCALE_LOG2E, y1*QSCALE_LOG2E);
    }
  } else {
    if (lane < 48){
      const float y0 = (v0 - mean)*rstd*g[c0]   + be[c0];
      const float y1 = (v1 - mean)*rstd*g[c0+1] + be[c0+1];
      ((u32*)Kaug)[(size_t)token*80 + lane] = pack2(y0, y1);
    } else {
      const int tt = n / HW_; const int rm = n % HW_;
      const int hh = rm / W_, ww = rm % W_;
      const int j0 = 4*(lane - 48);
      u32 p[2];
      #pragma unroll
      for (int h2 = 0; h2 < 2; ++h2){
        u32 w_ = 0;
        #pragma unroll
        for (int e = 0; e < 2; ++e){
          const int jj = j0 + 2*h2 + e;
          bool on = (jj < 14) ? (jj == hh) : (jj < 28) ? (jj-14 == ww)
                   : (jj < 36) ? (jj-28 == tt) : false;
          if (on) w_ |= (0x3F80u << (16*e));
        }
        p[h2] = w_;
      }
      *(uint2*)(Kaug + (size_t)token*CAUG_ + HD_ + j0) = make_uint2(p[0], p[1]);
    }
  }
}

// ---------------------------------------------------------------------------
// K2b: pool for v, writing transposed Vt [BH][96][N]. One wave per 8
// consecutive tokens; weights hoisted across the 8-token loop; lane writes
// its two channel rows as one uint4 (16B, 8 tokens) each.
// ---------------------------------------------------------------------------
__global__ __launch_bounds__(256) void k_pool_v(
    const bf_t* __restrict__ vr_, const float* __restrict__ wtv,
    const float* __restrict__ gv, const float* __restrict__ bv,
    bf_t* __restrict__ Vt){
  const int wid = threadIdx.x >> 6, lane = threadIdx.x & 63;
  const int tok0 = (blockIdx.x*4 + wid)*8;
  const int bh = tok0 / N_, n0 = tok0 % N_;
  const bf_t* base = vr_ + (size_t)bh*N_*HD_;
  const int c0 = (lane < 48) ? 2*lane : 0;
  float2 wgt[27];
  #pragma unroll
  for (int j = 0; j < 27; ++j) wgt[j] = *(const float2*)(wtv + j*HD_ + c0);
  const float gg0 = gv[c0], gg1 = gv[c0+1], bb0 = bv[c0], bb1 = bv[c0+1];
  u32 acc[8];
  #pragma unroll 1
  for (int t8 = 0; t8 < 8; ++t8){
    float v0, v1;
    conv_core(base, wgt, n0 + t8, c0, v0, v1);
    if (lane >= 48){ v0 = 0.f; v1 = 0.f; }
    float mean, rstd;
    ln_butterfly(v0, v1, mean, rstd);
    acc[t8] = pack2((v0 - mean)*rstd*gg0 + bb0, (v1 - mean)*rstd*gg1 + bb1);
  }
  if (lane < 48){
    u32 lo[4], hi[4];
    #pragma unroll
    for (int i = 0; i < 4; ++i){
      lo[i] = (acc[2*i] & 0xffffu)  | (acc[2*i+1] << 16);
      hi[i] = (acc[2*i] >> 16)      | (acc[2*i+1] & 0xffff0000u);
    }
    bf_t* r0 = Vt + ((size_t)bh*HD_ + c0)*N_ + n0;
    *(uint4*)r0        = make_uint4(lo[0], lo[1], lo[2], lo[3]);
    *(uint4*)(r0 + N_) = make_uint4(hi[0], hi[1], hi[2], hi[3]);
  }
}

// ---------------------------------------------------------------------------
// K3: rel-pos bias dots -> Qaug channels 96..131 (x log2e); 132..159 zeroed.
// ---------------------------------------------------------------------------
__global__ __launch_bounds__(64) void k_rel(const bf_t* __restrict__ qp,
    const float* __restrict__ rph, const float* __restrict__ rpw,
    const float* __restrict__ rpt, bf_t* __restrict__ Qaug){
  const int token = blockIdx.x;
  const int n = token % N_;
  const int tt = n / HW_; const int rm = n % HW_;
  const int hh = rm / W_, ww = rm % W_;
  __shared__ float qs[HD_];
  const int lane = threadIdx.x;
  if (lane < 48){
    const u32 u = ((const u32*)qp)[(size_t)token*48 + lane];
    qs[2*lane] = lo16(u); qs[2*lane+1] = hi16(u);
  }
  __syncthreads();
  if (lane < 36){
    const float* tb; int idx;
    if (lane < 14)      { tb = rph; idx = hh - lane      + 13; }
    else if (lane < 28) { tb = rpw; idx = ww - (lane-14) + 13; }
    else                { tb = rpt; idx = tt - (lane-28) +  7; }
    const float4* t4 = (const float4*)(tb + (size_t)idx*HD_);
    float acc = 0.f;
    #pragma unroll
    for (int i = 0; i < 24; ++i){
      const float4 rv = t4[i];
      acc += qs[4*i]*rv.x + qs[4*i+1]*rv.y + qs[4*i+2]*rv.z + qs[4*i+3]*rv.w;
    }
    Qaug[(size_t)token*CAUG_ + HD_ + lane] = f2b(acc * LOG2E);
  } else {
    Qaug[(size_t)token*CAUG_ + HD_ + lane] = 0;
  }
}

// ---------------------------------------------------------------------------
// K4: MFMA flash attention, in-block split-K (4 waves share a 16-row q-tile).
// ---------------------------------------------------------------------------
__global__ __launch_bounds__(256) void k_attn(
    const bf_t* __restrict__ Qaug, const bf_t* __restrict__ Kaug,
    const bf_t* __restrict__ Vt, const bf_t* __restrict__ qp,
    bf_t* __restrict__ attb){
  __shared__ __align__(16) short Pb[4][16][40];   // per-wave P tile (+8 pad)
  __shared__ float Os[4][16][96];                 // per-wave partial O
  __shared__ float ms[4][16], ls[4][16];          // per-wave partial m, l
  const int wid = threadIdx.x >> 6, lane = threadIdx.x & 63;
  const int bh = blockIdx.x / 98, qt = blockIdx.x % 98;
  const int q0 = qt*16;
  const int nl = lane & 15, quad = lane >> 4;

  bf16x8 qa[5];
  {
    const bf_t* Qrow = Qaug + ((size_t)bh*N_ + q0 + nl)*CAUG_ + quad*8;
    #pragma unroll
    for (int i = 0; i < 5; ++i) qa[i] = *(const bf16x8*)(Qrow + i*32);
  }
  const bf_t* Kb = Kaug + (size_t)bh*N_*CAUG_;
  const bf_t* Vb = Vt   + (size_t)bh*HD_*N_;
  short* Pw = &Pb[wid][0][0];

  f32x4 O[6];
  #pragma unroll
  for (int i = 0; i < 6; ++i) O[i] = (f32x4){0.f,0.f,0.f,0.f};
  float mc[4]   = {0.f,0.f,0.f,0.f};
  float rmax[4] = {-3e38f,-3e38f,-3e38f,-3e38f};
  float l[4]    = {0.f,0.f,0.f,0.f};

  auto s_tile = [&](int k0, int half){
    const bf_t* Krow = Kb + (size_t)(k0 + nl)*CAUG_ + quad*8;
    f32x4 s = (f32x4){0.f,0.f,0.f,0.f};
    #pragma unroll
    for (int i = 0; i < 5; ++i)
      s = __builtin_amdgcn_mfma_f32_16x16x32_bf16(qa[i], *(const bf16x8*)(Krow + i*32), s, 0, 0, 0);
    #pragma unroll
    for (int r = 0; r < 4; ++r){
      rmax[r] = fmaxf(rmax[r], s[r]);
      const float p = exp2f(s[r] - mc[r]);
      l[r] += p;
      Pw[(quad*4 + r)*40 + half*16 + nl] = (short)f2b(p);
    }
  };
  auto rescale = [&](){
    #pragma unroll
    for (int r = 0; r < 4; ++r){
      float tm = rmax[r];
      tm = fmaxf(tm, __shfl_xor(tm, 1));
      tm = fmaxf(tm, __shfl_xor(tm, 2));
      tm = fmaxf(tm, __shfl_xor(tm, 4));
      tm = fmaxf(tm, __shfl_xor(tm, 8));
      const float mn = fmaxf(mc[r], tm);
      const float al = exp2f(mc[r] - mn);
      mc[r] = mn; l[r] *= al;
      #pragma unroll
      for (int ct = 0; ct < 6; ++ct) O[ct][r] *= al;
    }
  };

  const int starts[5] = {0, 26, 52, 76, 98};
  const int t0 = starts[wid], npairs = (starts[wid+1] - t0) >> 1;
  #pragma unroll 1
  for (int pi = 0; pi < npairs; ++pi){
    const int k0 = (t0 + 2*pi)*16;
    s_tile(k0,      0);
    s_tile(k0 + 16, 1);
    const bf16x8 pa = *(const bf16x8*)(Pw + nl*40 + quad*8);
    const bf_t* Vrow = Vb + (size_t)nl*N_ + k0 + quad*8;
    #pragma unroll
    for (int ct = 0; ct < 6; ++ct)
      O[ct] = __builtin_amdgcn_mfma_f32_16x16x32_bf16(pa, *(const bf16x8*)(Vrow + (size_t)ct*16*N_), O[ct], 0, 0, 0);
    if ((pi % 7) == 6 || pi == npairs-1) rescale();
  }

  #pragma unroll
  for (int r = 0; r < 4; ++r){
    float ls_ = l[r];
    ls_ += __shfl_xor(ls_, 1); ls_ += __shfl_xor(ls_, 2);
    ls_ += __shfl_xor(ls_, 4); ls_ += __shfl_xor(ls_, 8);
    if (nl == 0){ ms[wid][quad*4 + r] = mc[r]; ls[wid][quad*4 + r] = ls_; }
    #pragma unroll
    for (int ct = 0; ct < 6; ++ct) Os[wid][quad*4 + r][ct*16 + nl] = O[ct][r];
  }
  __syncthreads();

  const int bb = bh >> 2, head = bh & 3;
  for (int e = threadIdx.x; e < 16*96; e += 256){
    const int row = e / 96, col = e % 96;
    const float m0 = ms[0][row], m1 = ms[1][row], m2 = ms[2][row], m3 = ms[3][row];
    const float mx = fmaxf(fmaxf(m0, m1), fmaxf(m2, m3));
    const float w0 = exp2f(m0 - mx), w1 = exp2f(m1 - mx),
                w2 = exp2f(m2 - mx), w3 = exp2f(m3 - mx);
    const float L = w0*ls[0][row] + w1*ls[1][row] + w2*ls[2][row] + w3*ls[3][row];
    const float A = w0*Os[0][row][col] + w1*Os[1][row][col]
                  + w2*Os[2][row][col] + w3*Os[3][row][col];
    const int qg = q0 + row;
    const float val = A/L + b2f(qp[((size_t)bh*N_ + qg)*HD_ + col]);
    attb[((size_t)(bb*N_ + qg))*DIM_ + head*HD_ + col] = f2b(val);
  }
}

// ---------------------------------------------------------------------------
// K5: output projection via MFMA: d_out[3136,384] = attb . Wpb^T + pb (fp32).
// ---------------------------------------------------------------------------
__global__ __launch_bounds__(256) void k_proj(const bf_t* __restrict__ Ab,
    const bf_t* __restrict__ Wpb, const float* __restrict__ pb,
    float* __restrict__ out){
  const int wid = threadIdx.x >> 6, lane = threadIdx.x & 63;
  const int wr = wid & 1, wc = wid >> 1;
  const int nl = lane & 15, quad = lane >> 4;
  const int r0 = blockIdx.x*64 + wr*32;
  const int c0 = blockIdx.y*128 + wc*64;
  f32x4 acc[2][4];
  #pragma unroll
  for (int i = 0; i < 2; ++i)
    #pragma unroll
    for (int j = 0; j < 4; ++j) acc[i][j] = (f32x4){0.f,0.f,0.f,0.f};
  const bf_t* A0 = Ab  + (size_t)(r0 + nl)*DIM_ + quad*8;
  const bf_t* B0 = Wpb + (size_t)(c0 + nl)*DIM_ + quad*8;
  #pragma unroll 2
  for (int k0 = 0; k0 < 12; ++k0){
    const bf16x8 a0 = *(const bf16x8*)(A0 + k0*32);
    const bf16x8 a1 = *(const bf16x8*)(A0 + 16*DIM_ + k0*32);
    bf16x8 bf[4];
    #pragma unroll
    for (int j = 0; j < 4; ++j) bf[j] = *(const bf16x8*)(B0 + (size_t)j*16*DIM_ + k0*32);
    #pragma unroll
    for (int j = 0; j < 4; ++j){
      acc[0][j] = __builtin_amdgcn_mfma_f32_16x16x32_bf16(a0, bf[j], acc[0][j], 0, 0, 0);
      acc[1][j] = __builtin_amdgcn_mfma_f32_16x16x32_bf16(a1, bf[j], acc[1][j], 0, 0, 0);
    }
  }
  #pragma unroll
  for (int i = 0; i < 2; ++i){
    #pragma unroll
    for (int r = 0; r < 4; ++r){
      const int m = r0 + i*16 + quad*4 + r;
      #pragma unroll
      for (int j = 0; j < 4; ++j){
        const int col = c0 + j*16 + nl;
        out[(size_t)m*DIM_ + col] = acc[i][j][r] + pb[col];
      }
    }
  }
}

// ---------------------------------------------------------------------------
extern "C" void kernel_launch(void* const* d_in, const int* in_sizes, int n_in,
                              void* d_out, int out_size, void* d_ws, size_t ws_size,
                              hipStream_t stream){
  const float* x      = (const float*)d_in[0];
  const float* qkv_w  = (const float*)d_in[1];
  const float* proj_w = (const float*)d_in[2];
  const float* proj_b = (const float*)d_in[3];
  const float* pqw    = (const float*)d_in[4];
  const float* pkw    = (const float*)d_in[5];
  const float* pvw    = (const float*)d_in[6];
  const float* nqw    = (const float*)d_in[7];
  const float* nqb    = (const float*)d_in[8];
  const float* nkw    = (const float*)d_in[9];
  const float* nkb    = (const float*)d_in[10];
  const float* nvw    = (const float*)d_in[11];
  const float* nvb    = (const float*)d_in[12];
  const float* rph    = (const float*)d_in[13];
  const float* rpw    = (const float*)d_in[14];
  const float* rpt    = (const float*)d_in[15];

  // Workspace (bytes), ~23.8 MB total. attb overlays raw_q after pooling.
  char* p = (char*)d_ws;
  const size_t RAW = (size_t)BH_*N_*HD_*2;       // 2,408,448 B
  const size_t AUG = (size_t)BH_*N_*CAUG_*2;     // 4,014,080 B
  bf_t* xb     = (bf_t*)(p);                     // 2,408,448 B
  bf_t* wqkvb  = (bf_t*)(p + RAW);               //   884,736 B
  bf_t* wprojb = (bf_t*)(p + RAW + 884736);      //   294,912 B
  char* p2 = p + RAW + 884736 + 294912;
  bf_t* raw_q  = (bf_t*)(p2);
  bf_t* raw_k  = (bf_t*)(p2 + RAW);
  bf_t* raw_v  = (bf_t*)(p2 + 2*RAW);
  bf_t* attb   = raw_q;                          // overlays raw_q after pooling
  bf_t* qp     = (bf_t*)(p2 + 3*RAW);
  bf_t* Qaug   = (bf_t*)(p2 + 4*RAW);
  bf_t* Kaug   = (bf_t*)(p2 + 4*RAW + AUG);
  bf_t* Vt     = (bf_t*)(p2 + 4*RAW + 2*AUG);
  float* wtq   = (float*)(p2 + 4*RAW + 3*AUG);   // 3 x 27x96 fp32 = 31,104 B
  float* wtk   = wtq + 27*HD_;
  float* wtv   = wtk + 27*HD_;

  k_cast   <<<CAST_BLOCKS,        256, 0, stream>>>(x, xb, qkv_w, wqkvb, proj_w, wprojb);
  k_prep   <<<31,                 256, 0, stream>>>(pqw, pkw, pvw, wtq, wtk, wtv);
  k_qkv    <<<dim3(BN_/64, 9),    256, 0, stream>>>(xb, wqkvb, raw_q, raw_k, raw_v);
  k_pool_qk<<<dim3(BHN_/4, 2),    256, 0, stream>>>(raw_q, raw_k, wtq, wtk,
                                                    nqw, nqb, nkw, nkb,
                                                    qp, Qaug, Kaug);
  k_pool_v <<<BHN_/32,            256, 0, stream>>>(raw_v, wtv, nvw, nvb, Vt);
  k_rel    <<<BHN_,                64, 0, stream>>>(qp, rph, rpw, rpt, Qaug);
  k_attn   <<<BH_*98,             256, 0, stream>>>(Qaug, Kaug, Vt, qp, attb);
  k_proj   <<<dim3(BN_/64, 3),    256, 0, stream>>>(attb, wprojb, proj_b, (float*)d_out);
}